// Round 1
// baseline (106652.063 us; speedup 1.0000x reference)
//
#include <hip/hip_runtime.h>
#include <stdint.h>

// Problem sizes (fixed)
#define TT 512
#define BB 64
#define DD 512

// ---------- small helpers ----------
__device__ __forceinline__ float bfl(uint32_t u){ return __uint_as_float(u << 16); }
__device__ __forceinline__ float bfh(uint32_t u){ return __uint_as_float(u & 0xffff0000u); }
__device__ __forceinline__ float bf2f(uint16_t u){ return __uint_as_float(((uint32_t)u) << 16); }
__device__ __forceinline__ uint16_t f2bf(float f){
  uint32_t u = __float_as_uint(f);
  u += 0x7fffu + ((u >> 16) & 1u);
  return (uint16_t)(u >> 16);
}
// tanh(x) = (e^{2x}-1)/(e^{2x}+1), sigmoid(x) = e^x/(e^x+1); exp via v_exp_f32
__device__ __forceinline__ float fast_tanh(float x){
  x = fminf(15.f, fmaxf(-15.f, x));
  float p = exp2f(x * 2.8853900817779268f);
  return (p - 1.f) / (p + 1.f);
}
__device__ __forceinline__ float fast_sig(float x){
  x = fminf(30.f, fmaxf(-30.f, x));
  float p = exp2f(x * 1.4426950408889634f);
  return p / (p + 1.f);
}

#define SCOPE_AG __HIP_MEMORY_SCOPE_AGENT

__device__ __forceinline__ void spin_until_neq(int* p, int v){
  while (__hip_atomic_load(p, __ATOMIC_ACQUIRE, SCOPE_AG) == v) __builtin_amdgcn_s_sleep(1);
}

// Two-level grid barrier for EXACTLY 256 workgroups. Sub-counter keyed by
// wg&7 (== XCD under default round-robin dispatch -> fast local fan-in;
// correctness does not depend on the mapping, only agent-scope atomics).
__device__ void gridbar(int* bar){
  __syncthreads();
  if (threadIdx.x == 0){
    int x = blockIdx.x & 7;
    int* scnt = bar + x * 32;
    int* sgen = bar + (8 + x) * 32;
    int* mcnt = bar + 16 * 32;
    int* mgen = bar + 17 * 32;
    int g = __hip_atomic_load(sgen, __ATOMIC_RELAXED, SCOPE_AG);
    int old = __hip_atomic_fetch_add(scnt, 1, __ATOMIC_ACQ_REL, SCOPE_AG);
    if (old == 31){
      __hip_atomic_store(scnt, 0, __ATOMIC_RELAXED, SCOPE_AG);
      int gm = __hip_atomic_load(mgen, __ATOMIC_RELAXED, SCOPE_AG);
      int om = __hip_atomic_fetch_add(mcnt, 1, __ATOMIC_ACQ_REL, SCOPE_AG);
      if (om == 7){
        __hip_atomic_store(mcnt, 0, __ATOMIC_RELAXED, SCOPE_AG);
        __hip_atomic_fetch_add(mgen, 1, __ATOMIC_RELEASE, SCOPE_AG);
      } else {
        spin_until_neq(mgen, gm);
      }
      __hip_atomic_fetch_add(sgen, 1, __ATOMIC_RELEASE, SCOPE_AG);
    } else {
      spin_until_neq(sgen, g);
    }
  }
  __syncthreads();
}

// 4-member group barrier (the 4 WGs sharing one batch element b; members are
// wg = b + 64k so they share an XCD under default dispatch).
__device__ __forceinline__ void groupbar(int* bar, int gid){
  __syncthreads();
  if (threadIdx.x == 0){
    int* c = bar + (32 + gid) * 32;
    int* g = bar + (96 + gid) * 32;
    int gv = __hip_atomic_load(g, __ATOMIC_RELAXED, SCOPE_AG);
    int old = __hip_atomic_fetch_add(c, 1, __ATOMIC_ACQ_REL, SCOPE_AG);
    if (old == 3){
      __hip_atomic_store(c, 0, __ATOMIC_RELAXED, SCOPE_AG);
      __hip_atomic_fetch_add(g, 1, __ATOMIC_RELEASE, SCOPE_AG);
    } else {
      spin_until_neq(g, gv);
    }
  }
  __syncthreads();
}

// ---------- K0: weight conversions / workspace init ----------
__global__ void prep_kernel(
  const float* __restrict__ x, const float* __restrict__ att_w1,
  const float* __restrict__ l0_wih, const float* __restrict__ l0_whh,
  const float* __restrict__ l0_bih, const float* __restrict__ l0_bhh,
  const float* __restrict__ l1_wih, const float* __restrict__ l1_whh,
  const float* __restrict__ l1_bih, const float* __restrict__ l1_bhh,
  uint16_t* __restrict__ xbf, uint16_t* __restrict__ wsbf,
  uint16_t* __restrict__ wih0, uint16_t* __restrict__ whh0,
  uint16_t* __restrict__ wih1, uint16_t* __restrict__ whh1,
  float* __restrict__ b0c, float* __restrict__ b1c, int* __restrict__ bar)
{
  int stride = gridDim.x * blockDim.x;
  int i0 = blockIdx.x * blockDim.x + threadIdx.x;
  for (int i = i0; i < TT*BB*DD; i += stride) xbf[i] = f2bf(x[i]);
  for (int i = i0; i < 512*512; i += stride)
    wsbf[i] = f2bf(att_w1[(i >> 9) * 1024 + (i & 511)]);   // ws = att_w1[:, :512]
  for (int i = i0; i < 2048*512; i += stride){
    wih0[i] = f2bf(l0_wih[i]); whh0[i] = f2bf(l0_whh[i]);
    wih1[i] = f2bf(l1_wih[i]); whh1[i] = f2bf(l1_whh[i]);
  }
  for (int i = i0; i < 2048; i += stride){
    b0c[i] = l0_bih[i] + l0_bhh[i];
    b1c[i] = l1_bih[i] + l1_bhh[i];
  }
  for (int i = i0; i < 8192; i += stride) bar[i] = 0;
}

// ---------- K1/K3: C[M][N] = A[M][K] @ B[N][K]^T + bias, tiled fp32 ----------
template<bool ABF, bool OBF>
__global__ __launch_bounds__(256) void gemm_bias(
  const void* __restrict__ A_, const float* __restrict__ B0, int ldb0,
  const float* __restrict__ B1, int ldb1, int nsplit,
  const float* __restrict__ bias0, const float* __restrict__ bias1,
  void* __restrict__ C_, int M, int N, int K)
{
  __shared__ float As[16][132];
  __shared__ float Bs[16][68];
  const int bm = blockIdx.x * 128, bn = blockIdx.y * 64;
  const int tid = threadIdx.x;
  const int m0 = (tid >> 4) * 8, n0 = (tid & 15) * 4;
  float acc[8][4] = {};
  for (int k0 = 0; k0 < K; k0 += 16){
    { // A tile 128x16
      int r = tid >> 1, c = (tid & 1) * 8;
      if (ABF){
        const uint16_t* ap = (const uint16_t*)A_ + (size_t)(bm + r) * K + k0 + c;
        uint4 v = *(const uint4*)ap;
        const uint16_t* pv = (const uint16_t*)&v;
        #pragma unroll
        for (int i = 0; i < 8; ++i) As[c + i][r] = bf2f(pv[i]);
      } else {
        const float* ap = (const float*)A_ + (size_t)(bm + r) * K + k0 + c;
        float4 v0 = *(const float4*)ap, v1 = *(const float4*)(ap + 4);
        As[c+0][r] = v0.x; As[c+1][r] = v0.y; As[c+2][r] = v0.z; As[c+3][r] = v0.w;
        As[c+4][r] = v1.x; As[c+5][r] = v1.y; As[c+6][r] = v1.z; As[c+7][r] = v1.w;
      }
    }
    { // B tile 64x16 (row n of weight matrix, possibly split across two arrays)
      int n = tid >> 2, cc = (tid & 3) * 4;
      int gn = bn + n;
      const float* bp = (gn < nsplit) ? (B0 + (size_t)gn * ldb0 + k0 + cc)
                                      : (B1 + (size_t)(gn - nsplit) * ldb1 + k0 + cc);
      float4 v = *(const float4*)bp;
      Bs[cc+0][n] = v.x; Bs[cc+1][n] = v.y; Bs[cc+2][n] = v.z; Bs[cc+3][n] = v.w;
    }
    __syncthreads();
    #pragma unroll
    for (int k = 0; k < 16; ++k){
      float a[8], bv[4];
      #pragma unroll
      for (int i = 0; i < 8; ++i) a[i] = As[k][m0 + i];
      #pragma unroll
      for (int j = 0; j < 4; ++j) bv[j] = Bs[k][n0 + j];
      #pragma unroll
      for (int i = 0; i < 8; ++i)
        #pragma unroll
        for (int j = 0; j < 4; ++j) acc[i][j] += a[i] * bv[j];
    }
    __syncthreads();
  }
  #pragma unroll
  for (int i = 0; i < 8; ++i){
    int gm = bm + m0 + i;
    #pragma unroll
    for (int j = 0; j < 4; ++j){
      int gn = bn + n0 + j;
      float bias = (gn < nsplit) ? bias0[gn] : bias1[gn - nsplit];
      float v = acc[i][j] + bias;
      if (OBF) ((uint16_t*)C_)[(size_t)gm * N + gn] = f2bf(v);
      else     ((float*)C_)[(size_t)gm * N + gn] = v;
    }
  }
}

// ---------- K2: bidirectional tanh-RNN scan; one WG per (dir, b) ----------
__global__ __launch_bounds__(512) void rnn_scan(
  const float* __restrict__ xp, const float* __restrict__ whf,
  const float* __restrict__ whb, const float* __restrict__ bhf,
  const float* __restrict__ bhb, uint16_t* __restrict__ hctx)
{
  __shared__ float hbuf[256];
  __shared__ float partial[512];
  const int wg = blockIdx.x, dir = wg >> 6, b = wg & 63, tid = threadIdx.x;
  const int j = tid & 255, half = tid >> 8;   // output j, k-half
  const float* wh = dir ? whb : whf;
  const float bj = (dir ? bhb : bhf)[j];
  uint32_t wreg[64];                           // 128 bf16 weights: wh[j][half*128 .. +128)
  #pragma unroll
  for (int m = 0; m < 64; ++m){
    int k = half * 128 + m * 2;
    wreg[m] = (uint32_t)f2bf(wh[j * 256 + k]) | ((uint32_t)f2bf(wh[j * 256 + k + 1]) << 16);
  }
  if (tid < 256) hbuf[tid] = 0.f;
  __syncthreads();
  for (int step = 0; step < TT; ++step){
    int t = dir ? (TT - 1 - step) : step;
    float acc = 0.f;
    const float* hb = hbuf + half * 128;
    #pragma unroll 16
    for (int m = 0; m < 64; ++m){
      uint32_t w = wreg[m];
      acc += bfl(w) * hb[m * 2] + bfh(w) * hb[m * 2 + 1];
    }
    partial[tid] = acc;
    __syncthreads();
    if (tid < 256){
      float v = partial[tid] + partial[tid + 256]
              + xp[(size_t)(t * 64 + b) * 512 + dir * 256 + j] + bj;
      v = fast_tanh(v);
      hbuf[j] = v;
      hctx[(size_t)(t * 64 + b) * 512 + dir * 256 + j] = f2bf(v);
    }
    __syncthreads();
  }
}

// ---------- LSTM gate phase (used for both cells) ----------
// WG owns units u0,u0+1 for all 64 b. thread: (gate = tid>>6, b = tid&63),
// computes g[gate][ul][b] for ul=0,1. k staged in 4 swizzled LDS tiles of 128.
__device__ __forceinline__ void lstm_phase(
  const uint16_t* __restrict__ xin, const uint16_t* __restrict__ hin,
  const uint16_t* __restrict__ wih, const uint16_t* __restrict__ whh,
  const float* __restrict__ bc, float& cs,
  uint16_t* __restrict__ hout, float* __restrict__ fout,
  uint16_t* sxs, uint16_t* sss, float* wt, float* glds, int u0, int tid)
{
  const int gate = tid >> 6, b = tid & 63;
  float acc0 = 0.f, acc1 = 0.f;
  #pragma unroll 1
  for (int kt = 0; kt < 4; ++kt){
    #pragma unroll
    for (int p = 0; p < 4; ++p){   // stage x / h tiles, 16B-block XOR swizzle vs bank conflicts
      int idx = p * 256 + tid;
      int rb = idx >> 4, blk = idx & 15;
      int dst = (rb * 16 + (blk ^ (rb & 15))) * 8;
      *(uint4*)(sxs + dst) = *(const uint4*)(xin + rb * 512 + kt * 128 + blk * 8);
      *(uint4*)(sss + dst) = *(const uint4*)(hin + rb * 512 + kt * 128 + blk * 8);
    }
    { // stage 16 weight rows (8 wih + 8 whh) as f32
      int r = tid >> 4, c8 = (tid & 15) * 8;
      int rr = r & 7;
      int jrow = (rr >> 1) * 512 + u0 + (rr & 1);
      const uint16_t* srcm = (r < 8) ? wih : whh;
      uint4 v = *(const uint4*)(srcm + (size_t)jrow * 512 + kt * 128 + c8);
      const uint16_t* pv = (const uint16_t*)&v;
      #pragma unroll
      for (int i = 0; i < 8; ++i) wt[r * 128 + c8 + i] = bf2f(pv[i]);
    }
    __syncthreads();
    const float* wi0 = wt + (gate * 2 + 0) * 128;
    const float* wi1 = wt + (gate * 2 + 1) * 128;
    const float* wh0 = wt + (8 + gate * 2) * 128;
    const float* wh1 = wt + (9 + gate * 2) * 128;
    #pragma unroll
    for (int o = 0; o < 16; ++o){
      int blk = o ^ (b & 15);
      uint4 xr = *(const uint4*)(sxs + (b * 16 + blk) * 8);
      uint4 sr = *(const uint4*)(sss + (b * 16 + blk) * 8);
      const uint32_t* xu = (const uint32_t*)&xr;
      const uint32_t* su = (const uint32_t*)&sr;
      #pragma unroll
      for (int h = 0; h < 4; ++h){
        float x0 = bfl(xu[h]), x1 = bfh(xu[h]);
        float s0 = bfl(su[h]), s1 = bfh(su[h]);
        int c = o * 8 + h * 2;
        acc0 += x0 * wi0[c]   + s0 * wh0[c];
        acc1 += x0 * wi1[c]   + s0 * wh1[c];
        acc0 += x1 * wi0[c+1] + s1 * wh0[c+1];
        acc1 += x1 * wi1[c+1] + s1 * wh1[c+1];
      }
    }
    __syncthreads();
  }
  acc0 += bc[gate * 512 + u0];
  acc1 += bc[gate * 512 + u0 + 1];
  glds[(gate * 2 + 0) * 64 + b] = acc0;
  glds[(gate * 2 + 1) * 64 + b] = acc1;
  __syncthreads();
  if (tid < 128){
    int b2 = tid & 63, ul = tid >> 6;
    float gi = glds[(0 + ul) * 64 + b2];
    float gf = glds[(2 + ul) * 64 + b2];
    float gg = glds[(4 + ul) * 64 + b2];
    float go = glds[(6 + ul) * 64 + b2];
    float c = fast_sig(gf) * cs + fast_sig(gi) * fast_tanh(gg);
    cs = c;
    float h = fast_sig(go) * fast_tanh(c);
    hout[b2 * 512 + u0 + ul] = f2bf(h);
    if (fout) fout[b2 * 512 + u0 + ul] = h;
  }
  __syncthreads();
}

// ---------- K4: persistent fused main scan ----------
// 256 WGs x 256 threads, all co-resident (1/CU). Per step:
//   [t>0] P_att (group-local: q, scores, ctx -> s)  | overlapped P3(t-1) done earlier
//   S1 gridbar -> P2 LSTM0 -> S2 gridbar -> P3 LSTM1 (+next P_att needs only h0: no 3rd bar)
__global__ __launch_bounds__(256) void main_loop(
  const uint16_t* __restrict__ ph, const uint16_t* __restrict__ hctx,
  const uint16_t* __restrict__ xbf, const uint16_t* __restrict__ wsbf,
  const uint16_t* __restrict__ wih0, const uint16_t* __restrict__ whh0,
  const uint16_t* __restrict__ wih1, const uint16_t* __restrict__ whh1,
  const float* __restrict__ b0c, const float* __restrict__ b1c,
  const float* __restrict__ attw2, const float* __restrict__ attb2,
  float* __restrict__ q, float* __restrict__ expE,
  uint16_t* __restrict__ sbf, uint16_t* __restrict__ h0bf,
  uint16_t* __restrict__ h1a, uint16_t* __restrict__ h1b,
  float* __restrict__ out, int* bar)
{
  __shared__ __align__(16) uint16_t sxs[8192];
  __shared__ __align__(16) uint16_t sss[8192];
  __shared__ __align__(16) float wt[2048];
  __shared__ float glds[512];
  __shared__ float hld[512];
  __shared__ float zred[4];

  const int wg = blockIdx.x, tid = threadIdx.x;
  const int b_att = wg & 63, kq = wg >> 6;    // attention group role
  const int u0 = wg * 2;                       // owned LSTM units
  const int lane = tid & 63, wv = tid >> 6;

  float w2r[8];
  #pragma unroll
  for (int i = 0; i < 8; ++i) w2r[i] = attw2[lane * 8 + i];
  const float b2s = attb2[0];

  float c0s = 0.f, c1s = 0.f;   // persistent cell states (thread tid<128: (b,ul))

  for (int i = wg * 256 + tid; i < 64 * 512; i += 256 * 256){
    sbf[i] = 0; h0bf[i] = 0; h1a[i] = 0; h1b[i] = 0;
  }

  #pragma unroll 1
  for (int t = 0; t < TT; ++t){
    if (t > 0){
      // ---- (i) q chunk: q[b][j] = sum_k ws[j,k] * h0[b,k], j in [kq*128, +128)
      for (int i = tid; i < 512; i += 256) hld[i] = bf2f(h0bf[b_att * 512 + i]);
      __syncthreads();
      {
        int jj = kq * 128 + (tid >> 1), half = tid & 1;
        const uint16_t* wrow = wsbf + jj * 512 + half * 256;
        const float* hrow = hld + half * 256;
        float acc = 0.f;
        for (int kk = 0; kk < 256; kk += 16){
          uint4 v0 = *(const uint4*)(wrow + kk);
          uint4 v1 = *(const uint4*)(wrow + kk + 8);
          const uint16_t* p0 = (const uint16_t*)&v0;
          const uint16_t* p1 = (const uint16_t*)&v1;
          #pragma unroll
          for (int i = 0; i < 8; ++i) acc += bf2f(p0[i]) * hrow[kk + i];
          #pragma unroll
          for (int i = 0; i < 8; ++i) acc += bf2f(p1[i]) * hrow[kk + 8 + i];
        }
        acc += __shfl_xor(acc, 1);
        if (half == 0) q[b_att * 512 + jj] = acc;
      }
      groupbar(bar, b_att);
      // ---- (ii) scores: e[tt,b] = tanh(w2 . tanh(q_b + ph[tt,b]) + b2); store exp(e)
      {
        float qr[8];
        #pragma unroll
        for (int i = 0; i < 8; ++i) qr[i] = q[b_att * 512 + lane * 8 + i];
        const uint16_t* pbase = ph + (size_t)(kq * 128 + wv * 32) * (64 * 512)
                                  + b_att * 512 + lane * 8;
        for (int it = 0; it < 32; it += 4){
          uint4 v[4];
          #pragma unroll
          for (int u = 0; u < 4; ++u)
            v[u] = *(const uint4*)(pbase + (size_t)(it + u) * (64 * 512));
          #pragma unroll
          for (int u = 0; u < 4; ++u){
            const uint16_t* pv = (const uint16_t*)&v[u];
            float part = 0.f;
            #pragma unroll
            for (int i = 0; i < 8; ++i){
              float z = fast_tanh(bf2f(pv[i]) + qr[i]);
              part += w2r[i] * z;
            }
            #pragma unroll
            for (int m = 32; m; m >>= 1) part += __shfl_xor(part, m);
            float e = fast_tanh(part + b2s);       // e in [-1,1] -> softmax needs no max trick
            if (lane == 0)
              expE[b_att * 512 + kq * 128 + wv * 32 + it + u] = exp2f(e * 1.4426950408889634f);
          }
        }
      }
      groupbar(bar, b_att);
      // ---- (iii) ctx + s: ctx[b,d] = sum_tt expE * hctx / Z ; s = h0 + ctx
      for (int i = tid; i < 512; i += 256) hld[i] = expE[b_att * 512 + i];
      __syncthreads();
      {
        float a0 = 0.f, a1 = 0.f, zp = 0.f;
        const uint16_t* hbase = hctx + (size_t)wv * (64 * 512) + b_att * 512
                                     + kq * 128 + lane * 2;
        for (int it = 0; it < 128; it += 8){
          uint32_t hv[8]; float ww[8];
          #pragma unroll
          for (int u = 0; u < 8; ++u){
            hv[u] = *(const uint32_t*)(hbase + (size_t)(it + u) * 4 * (64 * 512));
            ww[u] = hld[(it + u) * 4 + wv];
          }
          #pragma unroll
          for (int u = 0; u < 8; ++u){
            a0 += ww[u] * bfl(hv[u]); a1 += ww[u] * bfh(hv[u]); zp += ww[u];
          }
        }
        glds[wv * 128 + lane * 2]     = a0;
        glds[wv * 128 + lane * 2 + 1] = a1;
        if (lane == 0) zred[wv] = zp;
        __syncthreads();
        if (tid < 128){
          float Z = zred[0] + zred[1] + zred[2] + zred[3];
          float cv = (glds[tid] + glds[128 + tid] + glds[256 + tid] + glds[384 + tid]) / Z;
          int d = kq * 128 + tid;
          float sv = bf2f(h0bf[b_att * 512 + d]) + cv;
          sbf[b_att * 512 + d] = f2bf(sv);
        }
      }
    }
    gridbar(bar);   // S1: s(t) visible everywhere
    lstm_phase(xbf + (size_t)t * (64 * 512), sbf, wih0, whh0, b0c, c0s,
               h0bf, nullptr, sxs, sss, wt, glds, u0, tid);
    gridbar(bar);   // S2: h0(t) visible everywhere
    {
      const uint16_t* h1rd = (t & 1) ? h1b : h1a;  // double-buffered h1 (read t-1 / write t)
      uint16_t* h1wr = (t & 1) ? h1a : h1b;
      lstm_phase(h0bf, h1rd, wih1, whh1, b1c, c1s,
                 h1wr, out + (size_t)t * (64 * 512), sxs, sss, wt, glds, u0, tid);
    }
    // next P_att needs only h0(t) (synced at S2) -> no third barrier
  }
}

// ---------- host ----------
extern "C" void kernel_launch(void* const* d_in, const int* in_sizes, int n_in,
                              void* d_out, int out_size, void* d_ws, size_t ws_size,
                              hipStream_t stream)
{
  (void)in_sizes; (void)n_in; (void)out_size; (void)ws_size;
  const float* x       = (const float*)d_in[0];
  const float* rnn_wif = (const float*)d_in[1];
  const float* rnn_whf = (const float*)d_in[2];
  const float* rnn_bif = (const float*)d_in[3];
  const float* rnn_bhf = (const float*)d_in[4];
  const float* rnn_wib = (const float*)d_in[5];
  const float* rnn_whb = (const float*)d_in[6];
  const float* rnn_bib = (const float*)d_in[7];
  const float* rnn_bhb = (const float*)d_in[8];
  const float* att_w1  = (const float*)d_in[9];
  const float* att_b1  = (const float*)d_in[10];
  const float* att_w2  = (const float*)d_in[11];
  const float* att_b2  = (const float*)d_in[12];
  const float* l0_wih  = (const float*)d_in[13];
  const float* l0_whh  = (const float*)d_in[14];
  const float* l0_bih  = (const float*)d_in[15];
  const float* l0_bhh  = (const float*)d_in[16];
  const float* l1_wih  = (const float*)d_in[17];
  const float* l1_whh  = (const float*)d_in[18];
  const float* l1_bih  = (const float*)d_in[19];
  const float* l1_bhh  = (const float*)d_in[20];
  float* out = (float*)d_out;

  char* p = (char*)d_ws;
  auto take = [&](size_t bytes){ char* r = p; p += (bytes + 255) & ~(size_t)255; return r; };
  uint16_t* ph   = (uint16_t*)take((size_t)TT * BB * DD * 2);
  uint16_t* hctx = (uint16_t*)take((size_t)TT * BB * DD * 2);
  uint16_t* xbf  = (uint16_t*)take((size_t)TT * BB * DD * 2);
  uint16_t* wsbf = (uint16_t*)take(512 * 512 * 2);
  uint16_t* wih0 = (uint16_t*)take(2048 * 512 * 2);
  uint16_t* whh0 = (uint16_t*)take(2048 * 512 * 2);
  uint16_t* wih1 = (uint16_t*)take(2048 * 512 * 2);
  uint16_t* whh1 = (uint16_t*)take(2048 * 512 * 2);
  float* b0c  = (float*)take(2048 * 4);
  float* b1c  = (float*)take(2048 * 4);
  float* q    = (float*)take(64 * 512 * 4);
  float* expE = (float*)take(64 * 512 * 4);
  uint16_t* sbf  = (uint16_t*)take(64 * 512 * 2);
  uint16_t* h0bf = (uint16_t*)take(64 * 512 * 2);
  uint16_t* h1a  = (uint16_t*)take(64 * 512 * 2);
  uint16_t* h1b  = (uint16_t*)take(64 * 512 * 2);
  int* bar = (int*)take(8192 * 4);

  float* xp = out;   // d_out doubles as the RNN input-projection buffer (dead before out writes)

  prep_kernel<<<1024, 256, 0, stream>>>(x, att_w1, l0_wih, l0_whh, l0_bih, l0_bhh,
      l1_wih, l1_whh, l1_bih, l1_bhh, xbf, wsbf, wih0, whh0, wih1, whh1, b0c, b1c, bar);

  // xp[t,b, 0:256]=fwd proj, [256:512]=bwd proj (bias included)
  gemm_bias<false,false><<<dim3(256, 8), 256, 0, stream>>>(
      x, rnn_wif, 512, rnn_wib, 512, 256, rnn_bif, rnn_bib, (void*)xp, 32768, 512, 512);

  rnn_scan<<<128, 512, 0, stream>>>(xp, rnn_whf, rnn_whb, rnn_bhf, rnn_bhb, hctx);

  // proj_h = hctx @ wh^T + att_b1, wh rows = att_w1[:,512:] (row stride 1024)
  gemm_bias<true,true><<<dim3(256, 8), 256, 0, stream>>>(
      hctx, att_w1 + 512, 1024, nullptr, 1024, 512, att_b1, nullptr, (void*)ph, 32768, 512, 512);

  main_loop<<<256, 256, 0, stream>>>(ph, hctx, xbf, wsbf, wih0, whh0, wih1, whh1,
      b0c, b1c, att_w2, att_b2, q, expE, sbf, h0bf, h1a, h1b, out, bar);
}

// Round 2
// 41716.092 us; speedup vs baseline: 2.5566x; 2.5566x over previous
//
#include <hip/hip_runtime.h>
#include <stdint.h>

#define TT 512
#define BB 64
#define DD 512

// ---------- helpers ----------
__device__ __forceinline__ float bfl(uint32_t u){ return __uint_as_float(u << 16); }
__device__ __forceinline__ float bfh(uint32_t u){ return __uint_as_float(u & 0xffff0000u); }
__device__ __forceinline__ float bf2f(uint16_t u){ return __uint_as_float(((uint32_t)u) << 16); }
__device__ __forceinline__ uint16_t f2bf(float f){
  uint32_t u = __float_as_uint(f);
  u += 0x7fffu + ((u >> 16) & 1u);
  return (uint16_t)(u >> 16);
}
__device__ __forceinline__ float fast_tanh(float x){   // rcp-based, no slow fdiv
  x = fminf(15.f, fmaxf(-15.f, x));
  float p = __builtin_amdgcn_exp2f(x * 2.8853900817779268f);
  return (p - 1.f) * __builtin_amdgcn_rcpf(p + 1.f);
}
__device__ __forceinline__ float fast_sig(float x){
  x = fminf(30.f, fmaxf(-30.f, x));
  float p = __builtin_amdgcn_exp2f(x * 1.4426950408889634f);
  return p * __builtin_amdgcn_rcpf(p + 1.f);
}

#define SCOPE_AG __HIP_MEMORY_SCOPE_AGENT

// Relaxed agent-scope (sc1) accessors: write-through to L3, L2-bypass on read.
// No fences needed anywhere -> L2 never invalidated in the hot loop.
__device__ __forceinline__ uint32_t ald32(const uint32_t* p){
  return __hip_atomic_load((uint32_t*)p, __ATOMIC_RELAXED, SCOPE_AG);
}
__device__ __forceinline__ void ast32(uint32_t* p, uint32_t v){
  __hip_atomic_store(p, v, __ATOMIC_RELAXED, SCOPE_AG);
}
__device__ __forceinline__ float aldf(const float* p){
  return __uint_as_float(ald32((const uint32_t*)p));
}
__device__ __forceinline__ void astf(float* p, float v){
  ast32((uint32_t*)p, __float_as_uint(v));
}
__device__ __forceinline__ void spin_neq(int* p, int v){
  while (__hip_atomic_load(p, __ATOMIC_RELAXED, SCOPE_AG) == v)
    __builtin_amdgcn_s_sleep(1);
}

// Two-level grid barrier, 256 WGs. Relaxed atomics only; the __syncthreads()
// entering the barrier drains vmcnt(0) (sc1 stores ACKed at L3 coherence point).
__device__ void gridbar(int* bar){
  __syncthreads();
  if (threadIdx.x == 0){
    int x = blockIdx.x & 7;
    int* scnt = bar + x * 32;
    int* sgen = bar + (8 + x) * 32;
    int* mcnt = bar + 16 * 32;
    int* mgen = bar + 17 * 32;
    int g = __hip_atomic_load(sgen, __ATOMIC_RELAXED, SCOPE_AG);
    int old = __hip_atomic_fetch_add(scnt, 1, __ATOMIC_RELAXED, SCOPE_AG);
    if (old == 31){
      __hip_atomic_store(scnt, 0, __ATOMIC_RELAXED, SCOPE_AG);
      int gm = __hip_atomic_load(mgen, __ATOMIC_RELAXED, SCOPE_AG);
      int om = __hip_atomic_fetch_add(mcnt, 1, __ATOMIC_RELAXED, SCOPE_AG);
      if (om == 7){
        __hip_atomic_store(mcnt, 0, __ATOMIC_RELAXED, SCOPE_AG);
        __hip_atomic_fetch_add(mgen, 1, __ATOMIC_RELAXED, SCOPE_AG);
      } else {
        spin_neq(mgen, gm);
      }
      __hip_atomic_fetch_add(sgen, 1, __ATOMIC_RELAXED, SCOPE_AG);
    } else {
      spin_neq(sgen, g);
    }
  }
  __syncthreads();
}

// 4-member group barrier (WGs sharing batch element b: wg = b + 64k).
__device__ __forceinline__ void groupbar(int* bar, int gid){
  __syncthreads();
  if (threadIdx.x == 0){
    int* c = bar + (32 + gid) * 32;
    int* g = bar + (96 + gid) * 32;
    int gv = __hip_atomic_load(g, __ATOMIC_RELAXED, SCOPE_AG);
    int old = __hip_atomic_fetch_add(c, 1, __ATOMIC_RELAXED, SCOPE_AG);
    if (old == 3){
      __hip_atomic_store(c, 0, __ATOMIC_RELAXED, SCOPE_AG);
      __hip_atomic_fetch_add(g, 1, __ATOMIC_RELAXED, SCOPE_AG);
    } else {
      spin_neq(g, gv);
    }
  }
  __syncthreads();
}

// ---------- K0: conversions / init ----------
__global__ void prep_kernel(
  const float* __restrict__ x, const float* __restrict__ att_w1,
  const float* __restrict__ l0_wih, const float* __restrict__ l0_whh,
  const float* __restrict__ l0_bih, const float* __restrict__ l0_bhh,
  const float* __restrict__ l1_wih, const float* __restrict__ l1_whh,
  const float* __restrict__ l1_bih, const float* __restrict__ l1_bhh,
  uint16_t* __restrict__ xbf, uint16_t* __restrict__ wsbf,
  uint16_t* __restrict__ wih0, uint16_t* __restrict__ whh0,
  uint16_t* __restrict__ wih1, uint16_t* __restrict__ whh1,
  float* __restrict__ b0c, float* __restrict__ b1c, int* __restrict__ bar)
{
  int stride = gridDim.x * blockDim.x;
  int i0 = blockIdx.x * blockDim.x + threadIdx.x;
  for (int i = i0; i < TT*BB*DD; i += stride) xbf[i] = f2bf(x[i]);
  for (int i = i0; i < 512*512; i += stride)
    wsbf[i] = f2bf(att_w1[(i >> 9) * 1024 + (i & 511)]);
  for (int i = i0; i < 2048*512; i += stride){
    wih0[i] = f2bf(l0_wih[i]); whh0[i] = f2bf(l0_whh[i]);
    wih1[i] = f2bf(l1_wih[i]); whh1[i] = f2bf(l1_whh[i]);
  }
  for (int i = i0; i < 2048; i += stride){
    b0c[i] = l0_bih[i] + l0_bhh[i];
    b1c[i] = l1_bih[i] + l1_bhh[i];
  }
  for (int i = i0; i < 8192; i += stride) bar[i] = 0;
}

// ---------- K1/K3: C = A @ B^T + bias ----------
template<bool ABF, bool OBF>
__global__ __launch_bounds__(256) void gemm_bias(
  const void* __restrict__ A_, const float* __restrict__ B0, int ldb0,
  const float* __restrict__ B1, int ldb1, int nsplit,
  const float* __restrict__ bias0, const float* __restrict__ bias1,
  void* __restrict__ C_, int M, int N, int K)
{
  __shared__ float As[16][132];
  __shared__ float Bs[16][68];
  const int bm = blockIdx.x * 128, bn = blockIdx.y * 64;
  const int tid = threadIdx.x;
  const int m0 = (tid >> 4) * 8, n0 = (tid & 15) * 4;
  float acc[8][4] = {};
  for (int k0 = 0; k0 < K; k0 += 16){
    {
      int r = tid >> 1, c = (tid & 1) * 8;
      if (ABF){
        const uint16_t* ap = (const uint16_t*)A_ + (size_t)(bm + r) * K + k0 + c;
        uint4 v = *(const uint4*)ap;
        const uint16_t* pv = (const uint16_t*)&v;
        #pragma unroll
        for (int i = 0; i < 8; ++i) As[c + i][r] = bf2f(pv[i]);
      } else {
        const float* ap = (const float*)A_ + (size_t)(bm + r) * K + k0 + c;
        float4 v0 = *(const float4*)ap, v1 = *(const float4*)(ap + 4);
        As[c+0][r] = v0.x; As[c+1][r] = v0.y; As[c+2][r] = v0.z; As[c+3][r] = v0.w;
        As[c+4][r] = v1.x; As[c+5][r] = v1.y; As[c+6][r] = v1.z; As[c+7][r] = v1.w;
      }
    }
    {
      int n = tid >> 2, cc = (tid & 3) * 4;
      int gn = bn + n;
      const float* bp = (gn < nsplit) ? (B0 + (size_t)gn * ldb0 + k0 + cc)
                                      : (B1 + (size_t)(gn - nsplit) * ldb1 + k0 + cc);
      float4 v = *(const float4*)bp;
      Bs[cc+0][n] = v.x; Bs[cc+1][n] = v.y; Bs[cc+2][n] = v.z; Bs[cc+3][n] = v.w;
    }
    __syncthreads();
    #pragma unroll
    for (int k = 0; k < 16; ++k){
      float a[8], bv[4];
      #pragma unroll
      for (int i = 0; i < 8; ++i) a[i] = As[k][m0 + i];
      #pragma unroll
      for (int j = 0; j < 4; ++j) bv[j] = Bs[k][n0 + j];
      #pragma unroll
      for (int i = 0; i < 8; ++i)
        #pragma unroll
        for (int j = 0; j < 4; ++j) acc[i][j] += a[i] * bv[j];
    }
    __syncthreads();
  }
  #pragma unroll
  for (int i = 0; i < 8; ++i){
    int gm = bm + m0 + i;
    #pragma unroll
    for (int j = 0; j < 4; ++j){
      int gn = bn + n0 + j;
      float bias = (gn < nsplit) ? bias0[gn] : bias1[gn - nsplit];
      float v = acc[i][j] + bias;
      if (OBF) ((uint16_t*)C_)[(size_t)gm * N + gn] = f2bf(v);
      else     ((float*)C_)[(size_t)gm * N + gn] = v;
    }
  }
}

// ---------- K2: bi-RNN scan ----------
__global__ __launch_bounds__(512) void rnn_scan(
  const float* __restrict__ xp, const float* __restrict__ whf,
  const float* __restrict__ whb, const float* __restrict__ bhf,
  const float* __restrict__ bhb, uint16_t* __restrict__ hctx)
{
  __shared__ float hbuf[256];
  __shared__ float partial[512];
  const int wg = blockIdx.x, dir = wg >> 6, b = wg & 63, tid = threadIdx.x;
  const int j = tid & 255, half = tid >> 8;
  const float* wh = dir ? whb : whf;
  const float bj = (dir ? bhb : bhf)[j];
  uint32_t wreg[64];
  #pragma unroll
  for (int m = 0; m < 64; ++m){
    int k = half * 128 + m * 2;
    wreg[m] = (uint32_t)f2bf(wh[j * 256 + k]) | ((uint32_t)f2bf(wh[j * 256 + k + 1]) << 16);
  }
  if (tid < 256) hbuf[tid] = 0.f;
  __syncthreads();
  for (int step = 0; step < TT; ++step){
    int t = dir ? (TT - 1 - step) : step;
    float acc = 0.f;
    const float* hb = hbuf + half * 128;
    #pragma unroll 16
    for (int m = 0; m < 64; ++m){
      uint32_t w = wreg[m];
      acc += bfl(w) * hb[m * 2] + bfh(w) * hb[m * 2 + 1];
    }
    partial[tid] = acc;
    __syncthreads();
    if (tid < 256){
      float v = partial[tid] + partial[tid + 256]
              + xp[(size_t)(t * 64 + b) * 512 + dir * 256 + j] + bj;
      v = fast_tanh(v);
      hbuf[j] = v;
      hctx[(size_t)(t * 64 + b) * 512 + dir * 256 + j] = f2bf(v);
    }
    __syncthreads();
  }
}

// ---------- LSTM gate phase, 512-thread version ----------
// thread = gate(4) x ul(2) x b(64); one fp32 acc per thread.
template<bool XPLAIN>
__device__ __forceinline__ void lstm_phase(
  const void* __restrict__ xin,       // XPLAIN: const uint16_t* (plain); else const uint32_t* (sc1)
  const uint32_t* __restrict__ hin,   // sc1 u32 (b*256 + k/2)
  const uint16_t* __restrict__ wih, const uint16_t* __restrict__ whh,
  const float* __restrict__ bc, float& cA, float& cB,
  uint32_t* __restrict__ hout, float* __restrict__ fout,
  uint16_t* sxs, uint16_t* sss, float* wt, float* glds, int u0, int tid)
{
  const int g  = tid >> 7;
  const int ul = (tid >> 6) & 1;
  const int b  = tid & 63;
  float acc = 0.f;
  #pragma unroll 1
  for (int kt = 0; kt < 4; ++kt){
    #pragma unroll
    for (int p = 0; p < 2; ++p){   // stage 64b x 128k tiles (16B-block XOR swizzle)
      int idx = p * 512 + tid;
      int rb = idx >> 4, blk = idx & 15;
      int dst = (rb * 16 + (blk ^ (rb & 15))) * 8;
      if (XPLAIN){
        *(uint4*)(sxs + dst) = *(const uint4*)((const uint16_t*)xin + rb * 512 + kt * 128 + blk * 8);
      } else {
        uint32_t* d32 = (uint32_t*)(sxs + dst);
        const uint32_t* s32 = (const uint32_t*)xin + rb * 256 + kt * 64 + blk * 4;
        #pragma unroll
        for (int j = 0; j < 4; ++j) d32[j] = ald32(s32 + j);
      }
      {
        uint32_t* d32 = (uint32_t*)(sss + dst);
        const uint32_t* s32 = hin + rb * 256 + kt * 64 + blk * 4;
        #pragma unroll
        for (int j = 0; j < 4; ++j) d32[j] = ald32(s32 + j);
      }
    }
    { // stage 16 weight rows (8 wih + 8 whh) x 128 k as f32
      int r = tid >> 5, c4 = (tid & 31) * 4;
      int rr = r & 7;
      int jrow = (rr >> 1) * 512 + u0 + (rr & 1);
      const uint16_t* srcm = (r < 8) ? wih : whh;
      const uint16_t* sp = srcm + (size_t)jrow * 512 + kt * 128 + c4;
      uint2 v = *(const uint2*)sp;
      const uint16_t* pv = (const uint16_t*)&v;
      #pragma unroll
      for (int i = 0; i < 4; ++i) wt[r * 128 + c4 + i] = bf2f(pv[i]);
    }
    __syncthreads();
    const float* wi = wt + (g * 2 + ul) * 128;
    const float* wh = wt + (8 + g * 2 + ul) * 128;
    #pragma unroll
    for (int o = 0; o < 16; ++o){
      int blk = o ^ (b & 15);
      uint4 xr = *(const uint4*)(sxs + (b * 16 + blk) * 8);
      uint4 sr = *(const uint4*)(sss + (b * 16 + blk) * 8);
      #pragma unroll
      for (int h = 0; h < 4; ++h){
        uint32_t xv = ((const uint32_t*)&xr)[h], sv = ((const uint32_t*)&sr)[h];
        int c = o * 8 + h * 2;
        acc += bfl(xv) * wi[c]     + bfl(sv) * wh[c];
        acc += bfh(xv) * wi[c + 1] + bfh(sv) * wh[c + 1];
      }
    }
    __syncthreads();
  }
  acc += bc[g * 512 + u0 + ul];
  glds[g * 128 + ul * 64 + b] = acc;
  __syncthreads();
  if (tid < 64){
    float gi0 = glds[        tid], gi1 = glds[       64 + tid];
    float gf0 = glds[128   + tid], gf1 = glds[128 + 64 + tid];
    float gg0 = glds[256   + tid], gg1 = glds[256 + 64 + tid];
    float go0 = glds[384   + tid], go1 = glds[384 + 64 + tid];
    float c0 = fast_sig(gf0) * cA + fast_sig(gi0) * fast_tanh(gg0);
    float c1 = fast_sig(gf1) * cB + fast_sig(gi1) * fast_tanh(gg1);
    cA = c0; cB = c1;
    float h0v = fast_sig(go0) * fast_tanh(c0);
    float h1v = fast_sig(go1) * fast_tanh(c1);
    ast32(hout + tid * 256 + (u0 >> 1), (uint32_t)f2bf(h0v) | ((uint32_t)f2bf(h1v) << 16));
    if (fout) *(float2*)(fout + tid * 512 + u0) = make_float2(h0v, h1v);
  }
  __syncthreads();
}

// ---------- K4: persistent fused main scan (256 WGs x 512 threads) ----------
__global__ __launch_bounds__(512) void main_loop(
  const uint16_t* __restrict__ ph, const uint16_t* __restrict__ hctx,
  const uint16_t* __restrict__ xbf, const uint16_t* __restrict__ wsbf,
  const uint16_t* __restrict__ wih0, const uint16_t* __restrict__ whh0,
  const uint16_t* __restrict__ wih1, const uint16_t* __restrict__ whh1,
  const float* __restrict__ b0c, const float* __restrict__ b1c,
  const float* __restrict__ attw2, const float* __restrict__ attb2,
  float* __restrict__ q, float* __restrict__ expE,
  uint32_t* __restrict__ sbf, uint32_t* __restrict__ h0bf,
  uint32_t* __restrict__ h1a, uint32_t* __restrict__ h1b,
  float* __restrict__ out, int* bar)
{
  __shared__ __align__(16) uint16_t sxs[8192];
  __shared__ __align__(16) uint16_t sss[8192];
  __shared__ __align__(16) float wt[2048];
  __shared__ float glds[512];
  __shared__ float hldf[512];
  __shared__ float qld[512];
  __shared__ float w2ld[512];
  __shared__ float eld[512];
  __shared__ float spart[640];
  __shared__ float pctx[1024];
  __shared__ float zred[8];

  const int wg = blockIdx.x, tid = threadIdx.x;
  const int b_att = wg & 63, kq = wg >> 6;
  const int u0 = wg * 2;
  const int lane = tid & 63, wv = tid >> 6;

  w2ld[tid] = attw2[tid];
  const float b2s = attb2[0];
  float c0A = 0.f, c0B = 0.f, c1A = 0.f, c1B = 0.f;

  for (int i = wg * 512 + tid; i < 64 * 256; i += 256 * 512){
    ast32(sbf + i, 0); ast32(h0bf + i, 0); ast32(h1a + i, 0); ast32(h1b + i, 0);
  }

  #pragma unroll 1
  for (int t = 0; t < TT; ++t){
    if (t > 0){
      // ---- stage h0[b] -> hldf (f32)
      if (tid < 256){
        uint32_t v = ald32(h0bf + b_att * 256 + tid);
        hldf[tid * 2] = bfl(v); hldf[tid * 2 + 1] = bfh(v);
      }
      __syncthreads();
      // ---- q partial GEMV: j = kq*128 + (tid&127), k-seg = tid>>7
      {
        int jl = tid & 127, kseg = tid >> 7;
        const uint16_t* wrow = wsbf + (size_t)(kq * 128 + jl) * 512 + kseg * 128;
        const float* hseg = hldf + kseg * 128;
        float a0 = 0.f, a1 = 0.f;
        for (int k = 0; k < 128; k += 8){
          uint4 v = *(const uint4*)(wrow + k);
          const uint16_t* pv = (const uint16_t*)&v;
          #pragma unroll
          for (int i = 0; i < 8; i += 2){
            a0 += bf2f(pv[i]) * hseg[k + i];
            a1 += bf2f(pv[i + 1]) * hseg[k + i + 1];
          }
        }
        glds[kseg * 128 + jl] = a0 + a1;
      }
      __syncthreads();
      if (tid < 128)
        astf(q + b_att * 512 + kq * 128 + tid,
             glds[tid] + glds[128 + tid] + glds[256 + tid] + glds[384 + tid]);
      groupbar(bar, b_att);
      // ---- stage full q
      qld[tid] = aldf(q + b_att * 512 + tid);
      __syncthreads();
      // ---- scores (transposed: lane = tt, serial d-walk, no shuffles)
      {
        int ttl = (wv >> 2) * 64 + lane;
        int tt = kq * 128 + ttl;
        int d0 = (wv & 3) * 128;
        const uint16_t* pbase = ph + (size_t)tt * (64 * 512) + b_att * 512 + d0;
        float a0 = 0.f, a1 = 0.f;
        for (int d = 0; d < 128; d += 8){
          uint4 v = *(const uint4*)(pbase + d);
          const uint16_t* pv = (const uint16_t*)&v;
          #pragma unroll
          for (int i = 0; i < 8; i += 2){
            a0 += w2ld[d0 + d + i]     * fast_tanh(bf2f(pv[i])     + qld[d0 + d + i]);
            a1 += w2ld[d0 + d + i + 1] * fast_tanh(bf2f(pv[i + 1]) + qld[d0 + d + i + 1]);
          }
        }
        spart[ttl * 5 + (wv & 3)] = a0 + a1;
      }
      __syncthreads();
      if (tid < 128){
        float e = fast_tanh(spart[tid * 5] + spart[tid * 5 + 1] + spart[tid * 5 + 2]
                            + spart[tid * 5 + 3] + b2s);
        astf(expE + b_att * 512 + kq * 128 + tid,
             __builtin_amdgcn_exp2f(e * 1.4426950408889634f));
      }
      groupbar(bar, b_att);
      // ---- ctx: wave wv sums tt in [wv*64, +64), d-pair = kq*128 + lane*2
      eld[tid] = aldf(expE + b_att * 512 + tid);
      __syncthreads();
      {
        float a0 = 0.f, a1 = 0.f, zp = 0.f;
        const uint32_t* hbase = (const uint32_t*)hctx + (size_t)(wv * 64) * (64 * 256)
                                 + b_att * 256 + kq * 64 + lane;
        const float* ew = eld + wv * 64;
        for (int i = 0; i < 64; i += 8){
          uint32_t hv[8];
          #pragma unroll
          for (int u = 0; u < 8; ++u) hv[u] = hbase[(size_t)(i + u) * (64 * 256)];
          #pragma unroll
          for (int u = 0; u < 8; ++u){
            float w = ew[i + u];
            a0 += w * bfl(hv[u]); a1 += w * bfh(hv[u]); zp += w;
          }
        }
        pctx[wv * 128 + lane * 2] = a0;
        pctx[wv * 128 + lane * 2 + 1] = a1;
        if (lane == 0) zred[wv] = zp;
      }
      __syncthreads();
      if (tid < 64){
        float Z = zred[0] + zred[1] + zred[2] + zred[3]
                + zred[4] + zred[5] + zred[6] + zred[7];
        float rZ = __builtin_amdgcn_rcpf(Z);
        float cv0 = 0.f, cv1 = 0.f;
        #pragma unroll
        for (int w8 = 0; w8 < 8; ++w8){
          cv0 += pctx[w8 * 128 + tid * 2];
          cv1 += pctx[w8 * 128 + tid * 2 + 1];
        }
        float s0 = hldf[kq * 128 + tid * 2]     + cv0 * rZ;
        float s1 = hldf[kq * 128 + tid * 2 + 1] + cv1 * rZ;
        ast32(sbf + b_att * 256 + kq * 64 + tid,
              (uint32_t)f2bf(s0) | ((uint32_t)f2bf(s1) << 16));
      }
    }
    gridbar(bar);   // S1: s(t) visible
    lstm_phase<true>(xbf + (size_t)t * (64 * 512), sbf, wih0, whh0, b0c, c0A, c0B,
                     h0bf, nullptr, sxs, sss, wt, glds, u0, tid);
    gridbar(bar);   // S2: h0(t) visible
    {
      const uint32_t* h1rd = (t & 1) ? h1b : h1a;
      uint32_t* h1wr = (t & 1) ? h1a : h1b;
      lstm_phase<false>(h0bf, h1rd, wih1, whh1, b1c, c1A, c1B,
                        h1wr, out + (size_t)t * (64 * 512), sxs, sss, wt, glds, u0, tid);
    }
  }
}

// ---------- host ----------
extern "C" void kernel_launch(void* const* d_in, const int* in_sizes, int n_in,
                              void* d_out, int out_size, void* d_ws, size_t ws_size,
                              hipStream_t stream)
{
  (void)in_sizes; (void)n_in; (void)out_size; (void)ws_size;
  const float* x       = (const float*)d_in[0];
  const float* rnn_wif = (const float*)d_in[1];
  const float* rnn_whf = (const float*)d_in[2];
  const float* rnn_bif = (const float*)d_in[3];
  const float* rnn_bhf = (const float*)d_in[4];
  const float* rnn_wib = (const float*)d_in[5];
  const float* rnn_whb = (const float*)d_in[6];
  const float* rnn_bib = (const float*)d_in[7];
  const float* rnn_bhb = (const float*)d_in[8];
  const float* att_w1  = (const float*)d_in[9];
  const float* att_b1  = (const float*)d_in[10];
  const float* att_w2  = (const float*)d_in[11];
  const float* att_b2  = (const float*)d_in[12];
  const float* l0_wih  = (const float*)d_in[13];
  const float* l0_whh  = (const float*)d_in[14];
  const float* l0_bih  = (const float*)d_in[15];
  const float* l0_bhh  = (const float*)d_in[16];
  const float* l1_wih  = (const float*)d_in[17];
  const float* l1_whh  = (const float*)d_in[18];
  const float* l1_bih  = (const float*)d_in[19];
  const float* l1_bhh  = (const float*)d_in[20];
  float* out = (float*)d_out;

  char* p = (char*)d_ws;
  auto take = [&](size_t bytes){ char* r = p; p += (bytes + 255) & ~(size_t)255; return r; };
  uint16_t* ph   = (uint16_t*)take((size_t)TT * BB * DD * 2);
  uint16_t* hctx = (uint16_t*)take((size_t)TT * BB * DD * 2);
  uint16_t* xbf  = (uint16_t*)take((size_t)TT * BB * DD * 2);
  uint16_t* wsbf = (uint16_t*)take(512 * 512 * 2);
  uint16_t* wih0 = (uint16_t*)take(2048 * 512 * 2);
  uint16_t* whh0 = (uint16_t*)take(2048 * 512 * 2);
  uint16_t* wih1 = (uint16_t*)take(2048 * 512 * 2);
  uint16_t* whh1 = (uint16_t*)take(2048 * 512 * 2);
  float* b0c  = (float*)take(2048 * 4);
  float* b1c  = (float*)take(2048 * 4);
  float* q    = (float*)take(64 * 512 * 4);
  float* expE = (float*)take(64 * 512 * 4);
  uint32_t* sbf  = (uint32_t*)take(64 * 256 * 4);
  uint32_t* h0bf = (uint32_t*)take(64 * 256 * 4);
  uint32_t* h1a  = (uint32_t*)take(64 * 256 * 4);
  uint32_t* h1b  = (uint32_t*)take(64 * 256 * 4);
  int* bar = (int*)take(8192 * 4);

  float* xp = out;   // d_out doubles as RNN input-projection buffer

  prep_kernel<<<1024, 256, 0, stream>>>(x, att_w1, l0_wih, l0_whh, l0_bih, l0_bhh,
      l1_wih, l1_whh, l1_bih, l1_bhh, xbf, wsbf, wih0, whh0, wih1, whh1, b0c, b1c, bar);

  gemm_bias<false,false><<<dim3(256, 8), 256, 0, stream>>>(
      x, rnn_wif, 512, rnn_wib, 512, 256, rnn_bif, rnn_bib, (void*)xp, 32768, 512, 512);

  rnn_scan<<<128, 512, 0, stream>>>(xp, rnn_whf, rnn_whb, rnn_bhf, rnn_bhb, hctx);

  gemm_bias<true,true><<<dim3(256, 8), 256, 0, stream>>>(
      hctx, att_w1 + 512, 1024, nullptr, 1024, 512, att_b1, nullptr, (void*)ph, 32768, 512, 512);

  main_loop<<<256, 512, 0, stream>>>(ph, hctx, xbf, wsbf, wih0, whh0, wih1, whh1,
      b0c, b1c, att_w2, att_b2, q, expE, sbf, h0bf, h1a, h1b, out, bar);
}

// Round 3
// 28826.630 us; speedup vs baseline: 3.6998x; 1.4471x over previous
//
#include <hip/hip_runtime.h>
#include <stdint.h>

#define TT 512
#define BB 64
#define DD 512

// ---------- helpers ----------
__device__ __forceinline__ float bfl(uint32_t u){ return __uint_as_float(u << 16); }
__device__ __forceinline__ float bfh(uint32_t u){ return __uint_as_float(u & 0xffff0000u); }
__device__ __forceinline__ float bf2f(uint16_t u){ return __uint_as_float(((uint32_t)u) << 16); }
__device__ __forceinline__ uint16_t f2bf(float f){
  uint32_t u = __float_as_uint(f);
  u += 0x7fffu + ((u >> 16) & 1u);
  return (uint16_t)(u >> 16);
}
__device__ __forceinline__ uint32_t packbf(float a, float b){
  return (uint32_t)f2bf(a) | ((uint32_t)f2bf(b) << 16);
}
__device__ __forceinline__ float fast_tanh(float x){
  x = fminf(15.f, fmaxf(-15.f, x));
  float p = __builtin_amdgcn_exp2f(x * 2.8853900817779268f);
  return (p - 1.f) * __builtin_amdgcn_rcpf(p + 1.f);
}
__device__ __forceinline__ float fast_sig(float x){
  x = fminf(30.f, fmaxf(-30.f, x));
  float p = __builtin_amdgcn_exp2f(x * 1.4426950408889634f);
  return p * __builtin_amdgcn_rcpf(p + 1.f);
}

#define SCOPE_AG __HIP_MEMORY_SCOPE_AGENT

// ---- coherent (L1+L2-bypass, L3 coherence point) accessors ----
__device__ __forceinline__ uint32_t ld32_coh(const uint32_t* p){
  uint32_t r;
  asm volatile("global_load_dword %0, %1, off sc0 sc1\n\ts_waitcnt vmcnt(0)"
               : "=&v"(r) : "v"(p) : "memory");
  return r;
}
__device__ __forceinline__ uint4 ld16_coh(const void* p){
  uint4 r;
  asm volatile("global_load_dwordx4 %0, %1, off sc0 sc1\n\ts_waitcnt vmcnt(0)"
               : "=&v"(r) : "v"(p) : "memory");
  return r;
}
__device__ __forceinline__ void ld16x2_coh(const void* p, uint4& a, uint4& b){
  asm volatile(
    "global_load_dwordx4 %0, %2, off sc0 sc1\n\t"
    "global_load_dwordx4 %1, %2, off offset:16 sc0 sc1\n\t"
    "s_waitcnt vmcnt(0)"
    : "=&v"(a), "=&v"(b) : "v"(p) : "memory");
}
__device__ __forceinline__ void ld16x4_coh(const void* p0, const void* p1,
                                           uint4& a, uint4& b, uint4& c, uint4& d){
  asm volatile(
    "global_load_dwordx4 %0, %4, off sc0 sc1\n\t"
    "global_load_dwordx4 %1, %4, off offset:16 sc0 sc1\n\t"
    "global_load_dwordx4 %2, %5, off sc0 sc1\n\t"
    "global_load_dwordx4 %3, %5, off offset:16 sc0 sc1\n\t"
    "s_waitcnt vmcnt(0)"
    : "=&v"(a), "=&v"(b), "=&v"(c), "=&v"(d) : "v"(p0), "v"(p1) : "memory");
}
__device__ __forceinline__ void st32_coh(uint32_t* p, uint32_t v){
  asm volatile("global_store_dword %0, %1, off sc0 sc1" :: "v"(p), "v"(v) : "memory");
}
__device__ __forceinline__ void stf_coh(float* p, float v){
  st32_coh((uint32_t*)p, __float_as_uint(v));
}
__device__ __forceinline__ void drain_vm(){
  asm volatile("s_waitcnt vmcnt(0)" ::: "memory");
}
__device__ __forceinline__ void spin_neq(int* p, int v){
  while (__hip_atomic_load(p, __ATOMIC_RELAXED, SCOPE_AG) == v)
    __builtin_amdgcn_s_sleep(1);
}

// Two-level grid barrier, 256 WGs, relaxed agent-scope atomics (proven r1/r2).
__device__ void gridbar(int* bar){
  drain_vm();
  __syncthreads();
  if (threadIdx.x == 0){
    int x = blockIdx.x & 7;
    int* scnt = bar + x * 32;
    int* sgen = bar + (8 + x) * 32;
    int* mcnt = bar + 16 * 32;
    int* mgen = bar + 17 * 32;
    int g = __hip_atomic_load(sgen, __ATOMIC_RELAXED, SCOPE_AG);
    int old = __hip_atomic_fetch_add(scnt, 1, __ATOMIC_RELAXED, SCOPE_AG);
    if (old == 31){
      __hip_atomic_store(scnt, 0, __ATOMIC_RELAXED, SCOPE_AG);
      int gm = __hip_atomic_load(mgen, __ATOMIC_RELAXED, SCOPE_AG);
      int om = __hip_atomic_fetch_add(mcnt, 1, __ATOMIC_RELAXED, SCOPE_AG);
      if (om == 7){
        __hip_atomic_store(mcnt, 0, __ATOMIC_RELAXED, SCOPE_AG);
        __hip_atomic_fetch_add(mgen, 1, __ATOMIC_RELAXED, SCOPE_AG);
      } else {
        spin_neq(mgen, gm);
      }
      __hip_atomic_fetch_add(sgen, 1, __ATOMIC_RELAXED, SCOPE_AG);
    } else {
      spin_neq(sgen, g);
    }
  }
  __syncthreads();
}

// 4-member group barrier (WGs sharing batch element b: wg = b + 64k).
__device__ __forceinline__ void groupbar(int* bar, int gid){
  drain_vm();
  __syncthreads();
  if (threadIdx.x == 0){
    int* c = bar + (32 + gid) * 32;
    int* g = bar + (96 + gid) * 32;
    int gv = __hip_atomic_load(g, __ATOMIC_RELAXED, SCOPE_AG);
    int old = __hip_atomic_fetch_add(c, 1, __ATOMIC_RELAXED, SCOPE_AG);
    if (old == 3){
      __hip_atomic_store(c, 0, __ATOMIC_RELAXED, SCOPE_AG);
      __hip_atomic_fetch_add(g, 1, __ATOMIC_RELAXED, SCOPE_AG);
    } else {
      spin_neq(g, gv);
    }
  }
  __syncthreads();
}

// ---------- K0: small conversions / init ----------
__global__ void prep_kernel(
  const float* __restrict__ att_w1,
  const float* __restrict__ l0_bih, const float* __restrict__ l0_bhh,
  const float* __restrict__ l1_bih, const float* __restrict__ l1_bhh,
  uint32_t* __restrict__ wsT, float* __restrict__ b0c, float* __restrict__ b1c,
  int* __restrict__ bar)
{
  int stride = gridDim.x * blockDim.x;
  int i0 = blockIdx.x * blockDim.x + threadIdx.x;
  for (int i = i0; i < 256*512; i += stride){
    int k2 = i >> 9, j = i & 511;
    wsT[i] = packbf(att_w1[(size_t)j*1024 + 2*k2], att_w1[(size_t)j*1024 + 2*k2 + 1]);
  }
  for (int i = i0; i < 2048; i += stride){
    b0c[i] = l0_bih[i] + l0_bhh[i];
    b1c[i] = l1_bih[i] + l1_bhh[i];
  }
  for (int i = i0; i < 8192; i += stride) bar[i] = 0;
}

// ---------- K0b: x[t][b][k] f32 -> xt[t][k2][b] bf16-pairs ----------
__global__ __launch_bounds__(256) void xpose_x(const float* __restrict__ x,
                                               uint32_t* __restrict__ xt)
{
  __shared__ float tile[64][65];
  int t = blockIdx.x, kb = blockIdx.y;           // (512, 8)
  int r = threadIdx.x >> 2, c0 = (threadIdx.x & 3) * 16;
  const float* src = x + ((size_t)t*64 + r)*512 + kb*64 + c0;
  #pragma unroll
  for (int i = 0; i < 16; i += 4)
    *(float4*)&tile[r][c0 + i] = *(const float4*)(src + i);
  __syncthreads();
  int b = threadIdx.x & 63, k2l0 = threadIdx.x >> 6;
  for (int k2l = k2l0; k2l < 32; k2l += 4)
    xt[((size_t)t*256 + kb*32 + k2l)*64 + b] = packbf(tile[b][k2l*2], tile[b][k2l*2+1]);
}

// ---------- K2b: hctx[t][b][d] -> hctxT[b][d][t] (bf16) ----------
__global__ __launch_bounds__(256) void xpose_h(const uint16_t* __restrict__ hctx,
                                               uint16_t* __restrict__ hctxT)
{
  __shared__ uint16_t tile[64][72];
  int b = blockIdx.x, tb = blockIdx.y, db = blockIdx.z;   // (64, 8, 8)
  int tl = threadIdx.x >> 2, c0 = (threadIdx.x & 3) * 16;
  const uint16_t* src = hctx + ((size_t)(tb*64 + tl)*64 + b)*512 + db*64 + c0;
  *(uint4*)&tile[tl][c0]     = *(const uint4*)src;
  *(uint4*)&tile[tl][c0 + 8] = *(const uint4*)(src + 8);
  __syncthreads();
  int dl = threadIdx.x >> 2, t0 = (threadIdx.x & 3) * 16;
  uint16_t tmp[16];
  #pragma unroll
  for (int i = 0; i < 16; ++i) tmp[i] = tile[t0 + i][dl];
  uint16_t* dst = hctxT + ((size_t)b*512 + db*64 + dl)*512 + tb*64 + t0;
  *(uint4*)dst       = *(uint4*)tmp;
  *(uint4*)(dst + 8) = *(uint4*)(tmp + 8);
}

// ---------- K1/K3: C = A @ B^T + bias (unchanged from r2) ----------
template<bool ABF, bool OBF>
__global__ __launch_bounds__(256) void gemm_bias(
  const void* __restrict__ A_, const float* __restrict__ B0, int ldb0,
  const float* __restrict__ B1, int ldb1, int nsplit,
  const float* __restrict__ bias0, const float* __restrict__ bias1,
  void* __restrict__ C_, int M, int N, int K)
{
  __shared__ float As[16][132];
  __shared__ float Bs[16][68];
  const int bm = blockIdx.x * 128, bn = blockIdx.y * 64;
  const int tid = threadIdx.x;
  const int m0 = (tid >> 4) * 8, n0 = (tid & 15) * 4;
  float acc[8][4] = {};
  for (int k0 = 0; k0 < K; k0 += 16){
    {
      int r = tid >> 1, c = (tid & 1) * 8;
      if (ABF){
        const uint16_t* ap = (const uint16_t*)A_ + (size_t)(bm + r) * K + k0 + c;
        uint4 v = *(const uint4*)ap;
        const uint16_t* pv = (const uint16_t*)&v;
        #pragma unroll
        for (int i = 0; i < 8; ++i) As[c + i][r] = bf2f(pv[i]);
      } else {
        const float* ap = (const float*)A_ + (size_t)(bm + r) * K + k0 + c;
        float4 v0 = *(const float4*)ap, v1 = *(const float4*)(ap + 4);
        As[c+0][r] = v0.x; As[c+1][r] = v0.y; As[c+2][r] = v0.z; As[c+3][r] = v0.w;
        As[c+4][r] = v1.x; As[c+5][r] = v1.y; As[c+6][r] = v1.z; As[c+7][r] = v1.w;
      }
    }
    {
      int n = tid >> 2, cc = (tid & 3) * 4;
      int gn = bn + n;
      const float* bp = (gn < nsplit) ? (B0 + (size_t)gn * ldb0 + k0 + cc)
                                      : (B1 + (size_t)(gn - nsplit) * ldb1 + k0 + cc);
      float4 v = *(const float4*)bp;
      Bs[cc+0][n] = v.x; Bs[cc+1][n] = v.y; Bs[cc+2][n] = v.z; Bs[cc+3][n] = v.w;
    }
    __syncthreads();
    #pragma unroll
    for (int k = 0; k < 16; ++k){
      float a[8], bv[4];
      #pragma unroll
      for (int i = 0; i < 8; ++i) a[i] = As[k][m0 + i];
      #pragma unroll
      for (int j = 0; j < 4; ++j) bv[j] = Bs[k][n0 + j];
      #pragma unroll
      for (int i = 0; i < 8; ++i)
        #pragma unroll
        for (int j = 0; j < 4; ++j) acc[i][j] += a[i] * bv[j];
    }
    __syncthreads();
  }
  #pragma unroll
  for (int i = 0; i < 8; ++i){
    int gm = bm + m0 + i;
    #pragma unroll
    for (int j = 0; j < 4; ++j){
      int gn = bn + n0 + j;
      float bias = (gn < nsplit) ? bias0[gn] : bias1[gn - nsplit];
      float v = acc[i][j] + bias;
      if (OBF) ((uint16_t*)C_)[(size_t)gm * N + gn] = f2bf(v);
      else     ((float*)C_)[(size_t)gm * N + gn] = v;
    }
  }
}

// ---------- K2: bi-RNN scan (unchanged from r2) ----------
__global__ __launch_bounds__(512) void rnn_scan(
  const float* __restrict__ xp, const float* __restrict__ whf,
  const float* __restrict__ whb, const float* __restrict__ bhf,
  const float* __restrict__ bhb, uint16_t* __restrict__ hctx)
{
  __shared__ float hbuf[256];
  __shared__ float partial[512];
  const int wg = blockIdx.x, dir = wg >> 6, b = wg & 63, tid = threadIdx.x;
  const int j = tid & 255, half = tid >> 8;
  const float* wh = dir ? whb : whf;
  const float bj = (dir ? bhb : bhf)[j];
  uint32_t wreg[64];
  #pragma unroll
  for (int m = 0; m < 64; ++m){
    int k = half * 128 + m * 2;
    wreg[m] = packbf(wh[j * 256 + k], wh[j * 256 + k + 1]);
  }
  if (tid < 256) hbuf[tid] = 0.f;
  __syncthreads();
  for (int step = 0; step < TT; ++step){
    int t = dir ? (TT - 1 - step) : step;
    float acc = 0.f;
    const float* hb = hbuf + half * 128;
    #pragma unroll 16
    for (int m = 0; m < 64; ++m){
      uint32_t w = wreg[m];
      acc += bfl(w) * hb[m * 2] + bfh(w) * hb[m * 2 + 1];
    }
    partial[tid] = acc;
    __syncthreads();
    if (tid < 256){
      float v = partial[tid] + partial[tid + 256]
              + xp[(size_t)(t * 64 + b) * 512 + dir * 256 + j] + bj;
      v = fast_tanh(v);
      hbuf[j] = v;
      hctx[(size_t)(t * 64 + b) * 512 + dir * 256 + j] = f2bf(v);
    }
    __syncthreads();
  }
}

// ---------- LSTM gate phase (device fn, 1024 threads) ----------
// tiles: per-chunk [128 k2][64 b] bf16-pairs. weights: f32 LDS resident.
template<bool XCOH>
__device__ __forceinline__ void lstm_phase(
  const uint32_t* __restrict__ xin,   // [256][64] pairs (plain if !XCOH)
  const uint32_t* __restrict__ hin,   // [256][64] pairs (coherent)
  const float* __restrict__ wl,       // [16][512] f32 (8 wih rows, 8 whh rows)
  const float* __restrict__ bias8,    // [8]
  float& cs0, float& cs1,
  uint32_t* __restrict__ hog,         // [256][64] pair out, k2 = wgid
  float* __restrict__ outp,           // nullptr or out + t*32768
  uint32_t* tX, uint32_t* tS, float* part, float* glds,
  int u0, int tid, int wgid)
{
  const int b = tid & 63, ul = (tid >> 6) & 1, q8 = tid >> 7;
  float acc[4] = {0.f, 0.f, 0.f, 0.f};
  #pragma unroll 1
  for (int ch = 0; ch < 2; ++ch){
    {
      const int o = tid * 8;
      const uint32_t* xs = xin + ch * 8192 + o;
      const uint32_t* hs = hin + ch * 8192 + o;
      uint4 a0, a1, c0, c1;
      if (XCOH){
        ld16x4_coh(xs, hs, a0, a1, c0, c1);
      } else {
        a0 = *(const uint4*)xs; a1 = *(const uint4*)(xs + 4);
        ld16x2_coh(hs, c0, c1);
      }
      *(uint4*)(tX + o) = a0; *(uint4*)(tX + o + 4) = a1;
      *(uint4*)(tS + o) = c0; *(uint4*)(tS + o + 4) = c1;
    }
    __syncthreads();
    const int kk0 = ch * 256;
    #pragma unroll 4
    for (int p = 0; p < 16; ++p){
      int k2l = q8 * 16 + p;
      uint32_t xv = tX[k2l * 64 + b];
      uint32_t sv = tS[k2l * 64 + b];
      float x0 = bfl(xv), x1 = bfh(xv);
      float s0 = bfl(sv), s1 = bfh(sv);
      const float* wb = wl + ul * 512 + kk0 + k2l * 2;
      #pragma unroll
      for (int g = 0; g < 4; ++g){
        const float* wi = wb + g * 1024;
        const float* wh = wb + 4096 + g * 1024;
        acc[g] += x0 * wi[0] + x1 * wi[1] + s0 * wh[0] + s1 * wh[1];
      }
    }
    __syncthreads();
  }
  #pragma unroll
  for (int g = 0; g < 4; ++g) part[((g * 2 + ul) * 8 + q8) * 64 + b] = acc[g];
  __syncthreads();
  if (tid < 512){
    int g = tid >> 7, uu = (tid >> 6) & 1, bb = tid & 63;
    float s = bias8[g * 2 + uu];
    #pragma unroll
    for (int i = 0; i < 8; ++i) s += part[((g * 2 + uu) * 8 + i) * 64 + bb];
    glds[(g * 2 + uu) * 64 + bb] = s;
  }
  __syncthreads();
  if (tid < 64){
    float gi0 = glds[0 * 64 + tid], gi1 = glds[1 * 64 + tid];
    float gf0 = glds[2 * 64 + tid], gf1 = glds[3 * 64 + tid];
    float gg0 = glds[4 * 64 + tid], gg1 = glds[5 * 64 + tid];
    float go0 = glds[6 * 64 + tid], go1 = glds[7 * 64 + tid];
    float c0 = fast_sig(gf0) * cs0 + fast_sig(gi0) * fast_tanh(gg0);
    float c1 = fast_sig(gf1) * cs1 + fast_sig(gi1) * fast_tanh(gg1);
    cs0 = c0; cs1 = c1;
    float h0v = fast_sig(go0) * fast_tanh(c0);
    float h1v = fast_sig(go1) * fast_tanh(c1);
    st32_coh(hog + wgid * 64 + tid, packbf(h0v, h1v));
    if (outp) *(float2*)(outp + (size_t)tid * 512 + u0) = make_float2(h0v, h1v);
  }
  __syncthreads();
}

// ---------- K4: persistent fused main scan (256 WGs x 1024 threads, coop) ----------
__global__ __launch_bounds__(1024) void main_loop(
  const uint16_t* __restrict__ ph,     // [tt*64+b][512]
  const uint16_t* __restrict__ hctxT,  // [b][d][tt]
  const uint32_t* __restrict__ xt,     // [t][256][64] pairs
  const uint32_t* __restrict__ wsT,    // [256 k2][512 j] pairs
  const float* __restrict__ w0i, const float* __restrict__ w0h,
  const float* __restrict__ w1i, const float* __restrict__ w1h,
  const float* __restrict__ b0c, const float* __restrict__ b1c,
  const float* __restrict__ attw2, const float* __restrict__ attb2,
  float* __restrict__ qg, float* __restrict__ eg,     // [64][512] f32
  uint32_t* __restrict__ sg, uint32_t* __restrict__ h0g,
  uint32_t* __restrict__ h1ga, uint32_t* __restrict__ h1gb,  // [256][64] pairs
  float* __restrict__ out, int* bar)
{
  __shared__ float wl0[16 * 512];                 // 32KB persistent L0 weights
  __shared__ float wl1[16 * 512];                 // 32KB persistent L1 weights
  __shared__ __align__(16) uint32_t tileX[128 * 64];  // 32KB (arena A)
  __shared__ __align__(16) uint32_t tileS[128 * 64];  // 32KB (arena B)
  __shared__ float glds[512];
  __shared__ float w2l[512];
  __shared__ float bias0l[8], bias1l[8];
  __shared__ float zsh[1];

  const int wg = blockIdx.x, tid = threadIdx.x;
  const int b_att = wg & 63, kq = wg >> 6;
  const int u0 = wg * 2;

  // attention overlays (dead during LSTM phases)
  float* AF = (float*)tileX;      // hldf [0,512) | qld [512,1024) | eldf [1024,1536)
  float* BF = (float*)tileS;      // qpart [0,1152) | spart [1152,2304)
  float* hldf = AF;
  float* qld  = AF + 512;
  float* eldf = AF + 1024;
  float* qpart = BF;
  float* spart = BF + 1152;
  float* part  = (float*)tileX;   // LSTM gate partials (post-dot only)

  // ---- one-time LDS loads ----
  {
    int r = tid >> 6, c = (tid & 63) * 8;
    int rr = r & 7, g = rr >> 1, uu = rr & 1;
    const float* s0 = ((r < 8) ? w0i : w0h) + ((size_t)(g * 512 + u0 + uu)) * 512 + c;
    *(float4*)(wl0 + r * 512 + c)     = *(const float4*)s0;
    *(float4*)(wl0 + r * 512 + c + 4) = *(const float4*)(s0 + 4);
    const float* s1 = ((r < 8) ? w1i : w1h) + ((size_t)(g * 512 + u0 + uu)) * 512 + c;
    *(float4*)(wl1 + r * 512 + c)     = *(const float4*)s1;
    *(float4*)(wl1 + r * 512 + c + 4) = *(const float4*)(s1 + 4);
  }
  if (tid < 512) w2l[tid] = attw2[tid];
  if (tid < 8){
    int g = tid >> 1, uu = tid & 1;
    bias0l[tid] = b0c[g * 512 + u0 + uu];
    bias1l[tid] = b1c[g * 512 + u0 + uu];
  }
  const float b2s = attb2[0];
  float c0s0 = 0.f, c0s1 = 0.f, c1s0 = 0.f, c1s1 = 0.f;

  // zero shared-state buffers (visible after first gridbar)
  {
    int idx = wg * 1024 + tid;
    if (idx < 256 * 64){
      st32_coh(sg + idx, 0); st32_coh(h0g + idx, 0);
      st32_coh(h1ga + idx, 0); st32_coh(h1gb + idx, 0);
    }
  }
  __syncthreads();

  #pragma unroll 1
  for (int t = 0; t < TT; ++t){
    if (t > 0){
      // ---- A1: stage h0[b_att]; q-slice GEMV ----
      if (tid < 256){
        uint32_t v = ld32_coh(h0g + tid * 64 + b_att);
        hldf[tid * 2] = bfl(v); hldf[tid * 2 + 1] = bfh(v);
      }
      __syncthreads();
      {
        int jl = tid & 127, kseg = tid >> 7;
        const uint32_t* wp = wsT + (size_t)(kseg * 32) * 512 + kq * 128 + jl;
        float acc = 0.f;
        #pragma unroll 8
        for (int i = 0; i < 32; ++i){
          uint32_t w = wp[(size_t)i * 512];
          acc += bfl(w) * hldf[(kseg * 32 + i) * 2] + bfh(w) * hldf[(kseg * 32 + i) * 2 + 1];
        }
        qpart[jl * 9 + kseg] = acc;
      }
      __syncthreads();
      if (tid < 128){
        float s = 0.f;
        #pragma unroll
        for (int i = 0; i < 8; ++i) s += qpart[tid * 9 + i];
        stf_coh(qg + b_att * 512 + kq * 128 + tid, s);
      }
      groupbar(bar, b_att);
      // ---- A2: stage full q; scores ----
      if (tid < 128){
        uint4 v = ld16_coh(qg + b_att * 512 + tid * 4);
        *(uint4*)(qld + tid * 4) = v;
      }
      __syncthreads();
      {
        int ttl = tid >> 3, dseg = tid & 7;
        const uint16_t* pb = ph + ((size_t)(kq * 128 + ttl) * 64 + b_att) * 512 + dseg * 64;
        const float* qp = qld + dseg * 64;
        const float* wp = w2l + dseg * 64;
        float acc = 0.f;
        #pragma unroll 2
        for (int i = 0; i < 8; ++i){
          uint4 v = *(const uint4*)(pb + i * 8);
          const uint16_t* pv = (const uint16_t*)&v;
          #pragma unroll
          for (int j = 0; j < 8; ++j)
            acc += wp[i * 8 + j] * fast_tanh(bf2f(pv[j]) + qp[i * 8 + j]);
        }
        spart[ttl * 9 + dseg] = acc;
      }
      __syncthreads();
      if (tid < 128){
        float s = b2s;
        #pragma unroll
        for (int i = 0; i < 8; ++i) s += spart[tid * 9 + i];
        float e = fast_tanh(s);
        stf_coh(eg + b_att * 512 + kq * 128 + tid,
                __builtin_amdgcn_exp2f(e * 1.4426950408889634f));
      }
      groupbar(bar, b_att);
      // ---- A3: stage expE; Z; ctx; s ----
      if (tid < 128){
        uint4 v = ld16_coh(eg + b_att * 512 + tid * 4);
        *(uint4*)(eldf + tid * 4) = v;
      }
      __syncthreads();
      if (tid < 64){
        float zp = 0.f;
        #pragma unroll
        for (int j = 0; j < 8; ++j) zp += eldf[tid * 8 + j];
        #pragma unroll
        for (int m = 32; m; m >>= 1) zp += __shfl_xor(zp, m);
        if (tid == 0) zsh[0] = __builtin_amdgcn_rcpf(zp);
      }
      __syncthreads();
      {
        int dl = tid >> 3, tseg = tid & 7;
        const uint16_t* hb = hctxT + ((size_t)b_att * 512 + kq * 128 + dl) * 512 + tseg * 64;
        const float* ep = eldf + tseg * 64;
        float acc = 0.f;
        #pragma unroll 2
        for (int i = 0; i < 8; ++i){
          uint4 v = *(const uint4*)(hb + i * 8);
          const uint16_t* pv = (const uint16_t*)&v;
          #pragma unroll
          for (int j = 0; j < 8; ++j)
            acc += ep[i * 8 + j] * bf2f(pv[j]);
        }
        spart[dl * 9 + tseg] = acc;
      }
      __syncthreads();
      if (tid < 64){
        float c0 = 0.f, c1 = 0.f;
        #pragma unroll
        for (int i = 0; i < 8; ++i){
          c0 += spart[(2 * tid) * 9 + i];
          c1 += spart[(2 * tid + 1) * 9 + i];
        }
        float rz = zsh[0];
        float s0 = hldf[kq * 128 + 2 * tid]     + c0 * rz;
        float s1 = hldf[kq * 128 + 2 * tid + 1] + c1 * rz;
        st32_coh(sg + (kq * 64 + tid) * 64 + b_att, packbf(s0, s1));
      }
    }
    gridbar(bar);   // S1: s(t) visible grid-wide
    lstm_phase<false>(xt + (size_t)t * 16384, sg, wl0, bias0l, c0s0, c0s1,
                      h0g, nullptr, tileX, tileS, part, glds, u0, tid, wg);
    gridbar(bar);   // S2: h0(t) visible grid-wide
    {
      const uint32_t* h1rd = (t & 1) ? h1gb : h1ga;
      uint32_t* h1wr = (t & 1) ? h1ga : h1gb;
      lstm_phase<true>(h0g, h1rd, wl1, bias1l, c1s0, c1s1,
                       h1wr, out + (size_t)t * (64 * 512), tileX, tileS, part, glds,
                       u0, tid, wg);
    }
  }
}

// ---------- host ----------
extern "C" void kernel_launch(void* const* d_in, const int* in_sizes, int n_in,
                              void* d_out, int out_size, void* d_ws, size_t ws_size,
                              hipStream_t stream)
{
  (void)in_sizes; (void)n_in; (void)out_size; (void)ws_size;
  const float* x       = (const float*)d_in[0];
  const float* rnn_wif = (const float*)d_in[1];
  const float* rnn_whf = (const float*)d_in[2];
  const float* rnn_bif = (const float*)d_in[3];
  const float* rnn_bhf = (const float*)d_in[4];
  const float* rnn_wib = (const float*)d_in[5];
  const float* rnn_whb = (const float*)d_in[6];
  const float* rnn_bib = (const float*)d_in[7];
  const float* rnn_bhb = (const float*)d_in[8];
  const float* att_w1  = (const float*)d_in[9];
  const float* att_b1  = (const float*)d_in[10];
  const float* att_w2  = (const float*)d_in[11];
  const float* att_b2  = (const float*)d_in[12];
  const float* l0_wih  = (const float*)d_in[13];
  const float* l0_whh  = (const float*)d_in[14];
  const float* l0_bih  = (const float*)d_in[15];
  const float* l0_bhh  = (const float*)d_in[16];
  const float* l1_wih  = (const float*)d_in[17];
  const float* l1_whh  = (const float*)d_in[18];
  const float* l1_bih  = (const float*)d_in[19];
  const float* l1_bhh  = (const float*)d_in[20];
  float* out = (float*)d_out;

  char* p = (char*)d_ws;
  auto take = [&](size_t bytes){ char* r = p; p += (bytes + 255) & ~(size_t)255; return r; };
  uint16_t* ph    = (uint16_t*)take((size_t)TT * BB * DD * 2);
  uint16_t* hctx  = (uint16_t*)take((size_t)TT * BB * DD * 2);
  uint16_t* hctxT = (uint16_t*)take((size_t)TT * BB * DD * 2);
  uint32_t* xt    = (uint32_t*)take((size_t)TT * 256 * 64 * 4);
  uint32_t* wsT   = (uint32_t*)take(256 * 512 * 4);
  float* b0c = (float*)take(2048 * 4);
  float* b1c = (float*)take(2048 * 4);
  float* qg  = (float*)take(64 * 512 * 4);
  float* eg  = (float*)take(64 * 512 * 4);
  uint32_t* sg   = (uint32_t*)take(256 * 64 * 4);
  uint32_t* h0g  = (uint32_t*)take(256 * 64 * 4);
  uint32_t* h1ga = (uint32_t*)take(256 * 64 * 4);
  uint32_t* h1gb = (uint32_t*)take(256 * 64 * 4);
  int* bar = (int*)take(8192 * 4);

  float* xp = out;   // d_out doubles as RNN input-projection buffer

  prep_kernel<<<256, 256, 0, stream>>>(att_w1, l0_bih, l0_bhh, l1_bih, l1_bhh,
                                       wsT, b0c, b1c, bar);
  xpose_x<<<dim3(512, 8), 256, 0, stream>>>(x, xt);

  gemm_bias<false,false><<<dim3(256, 8), 256, 0, stream>>>(
      x, rnn_wif, 512, rnn_wib, 512, 256, rnn_bif, rnn_bib, (void*)xp, 32768, 512, 512);

  rnn_scan<<<128, 512, 0, stream>>>(xp, rnn_whf, rnn_whb, rnn_bhf, rnn_bhb, hctx);

  xpose_h<<<dim3(64, 8, 8), 256, 0, stream>>>(hctx, hctxT);

  gemm_bias<true,true><<<dim3(256, 8), 256, 0, stream>>>(
      hctx, att_w1 + 512, 1024, nullptr, 1024, 512, att_b1, nullptr, (void*)ph, 32768, 512, 512);

  {
    const uint16_t* ph_c = ph; const uint16_t* hctxT_c = hctxT;
    const uint32_t* xt_c = xt; const uint32_t* wsT_c = wsT;
    const float *w0i = l0_wih, *w0h = l0_whh, *w1i = l1_wih, *w1h = l1_whh;
    const float *b0c_c = b0c, *b1c_c = b1c, *aw2 = att_w2, *ab2 = att_b2;
    float *qg_ = qg, *eg_ = eg, *out_ = out;
    uint32_t *sg_ = sg, *h0g_ = h0g, *h1ga_ = h1ga, *h1gb_ = h1gb;
    int* bar_ = bar;
    void* args[] = {
      (void*)&ph_c, (void*)&hctxT_c, (void*)&xt_c, (void*)&wsT_c,
      (void*)&w0i, (void*)&w0h, (void*)&w1i, (void*)&w1h,
      (void*)&b0c_c, (void*)&b1c_c, (void*)&aw2, (void*)&ab2,
      (void*)&qg_, (void*)&eg_, (void*)&sg_, (void*)&h0g_, (void*)&h1ga_, (void*)&h1gb_,
      (void*)&out_, (void*)&bar_
    };
    hipLaunchCooperativeKernel((void*)main_loop, dim3(256), dim3(1024), args, 0, stream);
  }
}